// Round 1
// baseline (480.867 us; speedup 1.0000x reference)
//
#include <hip/hip_runtime.h>
#include <math.h>

#define N 8192
#define F 8
#define RPW 4                 // rows per wave
#define WPB 4                 // waves per block
#define RPB (RPW * WPB)       // 16 rows per block
#define JSPLIT 4
#define JCHUNK (N / JSPLIT)   // 2048 columns per block
#define TJ 256                // j-tile staged in LDS per iteration
#define NIT (JCHUNK / TJ)     // 8 iterations

// msg[i][f] = sum_j max(A[i][j], fid_adj[i][j]) * X[j][f]
// fid_adj = 1 iff (xn_i . xn_j)^2 >= 0.9 and i != j, xn = X/(||X||+1e-12).
// A ~ U[0,1) so max(a,1)==1 exactly -> adj = sel ? 1.0f : a.
// X[j] reconstructed as xn[j]*s[j] (identical math to prior verified kernel).
//
// v2: LDS-staged j-tiles (normalize fused into staging), k-major LDS layout
// for conflict-free ds_read_b128, A prefetched one tile ahead, xi hoisted to
// SGPRs via readfirstlane to keep VGPR <= 128 at 4 blocks/CU.
__global__ __launch_bounds__(256, 4) void msg_pass_kernel(
    const float* __restrict__ A, const float* __restrict__ X,
    float* __restrict__ msg) {
  // Row (4*l + k) of the staged 256-row tile lives at [k][l][*]:
  // inner-loop reads lds_x[k][lane] are lane-contiguous 32B -> no conflicts.
  __shared__ __align__(16) float lds_x[4][64][F];
  __shared__ float lds_s[4][64];

  const int t = threadIdx.x;
  const int lane = t & 63;
  const int wave = t >> 6;
  const int i0 = blockIdx.x * RPB + wave * RPW;
  const int jbase = blockIdx.y * JCHUNK;

  // Wave's 4 source rows, normalized inline (identical op sequence to the
  // old normalize_kernel -> bit-identical xn). Wave-uniform -> SGPRs.
  float xi[RPW][F];
#pragma unroll
  for (int r = 0; r < RPW; ++r) {
    const float4* xp = (const float4*)(X + (size_t)(i0 + r) * F);
    const float4 lo = xp[0], hi = xp[1];
    const float ss2 = lo.x * lo.x + lo.y * lo.y + lo.z * lo.z + lo.w * lo.w +
                      hi.x * hi.x + hi.y * hi.y + hi.z * hi.z + hi.w * hi.w;
    const float inv = 1.0f / (sqrtf(ss2) + 1e-12f);
    float v[F] = {lo.x * inv, lo.y * inv, lo.z * inv, lo.w * inv,
                  hi.x * inv, hi.y * inv, hi.z * inv, hi.w * inv};
#pragma unroll
    for (int f = 0; f < F; ++f)
      xi[r][f] = __int_as_float(
          __builtin_amdgcn_readfirstlane(__float_as_int(v[f])));
  }

  float acc[RPW][F];
#pragma unroll
  for (int r = 0; r < RPW; ++r)
#pragma unroll
    for (int f = 0; f < F; ++f) acc[r][f] = 0.f;

  // A prefetch for tile 0: lane covers 4 consecutive cols -> coalesced 1KB/row.
  float4 aR[RPW];
  {
    const size_t j0 = (size_t)jbase + (size_t)lane * 4;
#pragma unroll
    for (int r = 0; r < RPW; ++r)
      aR[r] = *(const float4*)(A + (size_t)(i0 + r) * N + j0);
  }

  for (int it = 0; it < NIT; ++it) {
    // Stage + normalize this tile's row `t` into k-major slot [t&3][t>>2].
    {
      const float4* xp =
          (const float4*)(X + (size_t)(jbase + it * TJ + t) * F);
      const float4 lo = xp[0], hi = xp[1];
      const float ss2 = lo.x * lo.x + lo.y * lo.y + lo.z * lo.z + lo.w * lo.w +
                        hi.x * hi.x + hi.y * hi.y + hi.z * hi.z + hi.w * hi.w;
      const float nrm = sqrtf(ss2) + 1e-12f;
      const float inv = 1.0f / nrm;
      float4* xrow = (float4*)&lds_x[t & 3][t >> 2][0];
      xrow[0] = make_float4(lo.x * inv, lo.y * inv, lo.z * inv, lo.w * inv);
      xrow[1] = make_float4(hi.x * inv, hi.y * inv, hi.z * inv, hi.w * inv);
      lds_s[t & 3][t >> 2] = nrm;
    }
    __syncthreads();

    // Prefetch next tile's A while this tile computes (HBM stream in flight).
    float4 aN[RPW];
    if (it + 1 < NIT) {
      const size_t j0 = (size_t)jbase + (size_t)(it + 1) * TJ + (size_t)lane * 4;
#pragma unroll
      for (int r = 0; r < RPW; ++r)
        aN[r] = *(const float4*)(A + (size_t)(i0 + r) * N + j0);
    }

    const int jl = jbase + it * TJ + lane * 4;
#pragma unroll
    for (int k = 0; k < 4; ++k) {
      const float4 xlo = *(const float4*)&lds_x[k][lane][0];
      const float4 xhi = *(const float4*)&lds_x[k][lane][4];
      const float sj = lds_s[k][lane];
      const float xj[F] = {xlo.x, xlo.y, xlo.z, xlo.w,
                           xhi.x, xhi.y, xhi.z, xhi.w};
      const int j = jl + k;
#pragma unroll
      for (int r = 0; r < RPW; ++r) {
        float dot = 0.f;
#pragma unroll
        for (int f = 0; f < F; ++f) dot += xi[r][f] * xj[f];
        const bool sel = (dot * dot >= 0.9f) && (j != i0 + r);
        const float av = (k == 0)   ? aR[r].x
                         : (k == 1) ? aR[r].y
                         : (k == 2) ? aR[r].z
                                    : aR[r].w;
        const float coef = (sel ? 1.0f : av) * sj;  // X[j] = xn[j]*s[j]
#pragma unroll
        for (int f = 0; f < F; ++f) acc[r][f] += coef * xj[f];
      }
    }
    __syncthreads();  // LDS consumed; safe to overwrite next iteration
    if (it + 1 < NIT) {
#pragma unroll
      for (int r = 0; r < RPW; ++r) aR[r] = aN[r];
    }
  }

  // Wave butterfly reduce; lane (r*8+f) owns that output's atomic.
#pragma unroll
  for (int r = 0; r < RPW; ++r) {
#pragma unroll
    for (int f = 0; f < F; ++f) {
      float v = acc[r][f];
#pragma unroll
      for (int off = 1; off < 64; off <<= 1) v += __shfl_xor(v, off, 64);
      if (lane == r * F + f) atomicAdd(msg + (size_t)(i0 + r) * F + f, v);
    }
  }
}

__device__ __forceinline__ float sigmoidf_(float z) {
  return 1.0f / (1.0f + expf(-z));
}

// Per-node MLP chain. Weights are (fan_in, fan_out) row-major.
__global__ __launch_bounds__(256) void mlp_kernel(
    const float* __restrict__ msg,
    const float* __restrict__ W_fm, const float* __restrict__ b_fm,
    const float* __restrict__ W_c1, const float* __restrict__ b_c1,
    const float* __restrict__ W_p1, const float* __restrict__ b_p1,
    const float* __restrict__ W_c2, const float* __restrict__ b_c2,
    const float* __restrict__ W_p2, const float* __restrict__ b_p2,
    const float* __restrict__ W_c3, const float* __restrict__ b_c3,
    const float* __restrict__ W_h, const float* __restrict__ b_h,
    float* __restrict__ out) {
  const int i = blockIdx.x * blockDim.x + threadIdx.x;
  if (i >= N) return;

  float h0[8];
#pragma unroll
  for (int f = 0; f < 8; ++f) h0[f] = msg[(size_t)i * 8 + f];

  float h1[16];
#pragma unroll
  for (int o = 0; o < 16; ++o) {
    float z = b_fm[o];
#pragma unroll
    for (int k = 0; k < 8; ++k) z += h0[k] * W_fm[k * 16 + o];
    h1[o] = tanhf(z);
  }
  float h2[16];
#pragma unroll
  for (int o = 0; o < 16; ++o) {
    float z = b_c1[o];
#pragma unroll
    for (int k = 0; k < 16; ++k) z += h1[k] * W_c1[k * 16 + o];
    h2[o] = tanhf(z);
  }
  float h3[12];
#pragma unroll
  for (int o = 0; o < 12; ++o) {
    float z = b_p1[o];
#pragma unroll
    for (int k = 0; k < 16; ++k) z += h2[k] * W_p1[k * 12 + o];
    h3[o] = tanhf(z);
  }
  float h4[8];
#pragma unroll
  for (int o = 0; o < 8; ++o) {
    float z = b_c2[o];
#pragma unroll
    for (int k = 0; k < 12; ++k) z += h3[k] * W_c2[k * 8 + o];
    h4[o] = tanhf(z);
  }
  float h5[4];
#pragma unroll
  for (int o = 0; o < 4; ++o) {
    float z = b_p2[o];
#pragma unroll
    for (int k = 0; k < 8; ++k) z += h4[k] * W_p2[k * 4 + o];
    h5[o] = tanhf(z);
  }
  float h6[4];
#pragma unroll
  for (int o = 0; o < 4; ++o) {
    float z = b_c3[o];
#pragma unroll
    for (int k = 0; k < 4; ++k) z += h5[k] * W_c3[k * 4 + o];
    h6[o] = tanhf(z);
  }
  float z = b_h[0];
#pragma unroll
  for (int k = 0; k < 4; ++k) z += h6[k] * W_h[k];
  out[i] = sigmoidf_(z);
}

extern "C" void kernel_launch(void* const* d_in, const int* in_sizes, int n_in,
                              void* d_out, int out_size, void* d_ws,
                              size_t ws_size, hipStream_t stream) {
  const float* A = (const float*)d_in[0];
  const float* X = (const float*)d_in[1];
  const float* W_fm = (const float*)d_in[2];
  const float* b_fm = (const float*)d_in[3];
  const float* W_c1 = (const float*)d_in[4];
  const float* b_c1 = (const float*)d_in[5];
  const float* W_p1 = (const float*)d_in[6];
  const float* b_p1 = (const float*)d_in[7];
  const float* W_c2 = (const float*)d_in[8];
  const float* b_c2 = (const float*)d_in[9];
  const float* W_p2 = (const float*)d_in[10];
  const float* b_p2 = (const float*)d_in[11];
  const float* W_c3 = (const float*)d_in[12];
  const float* b_c3 = (const float*)d_in[13];
  const float* W_h = (const float*)d_in[14];
  const float* b_h = (const float*)d_in[15];
  float* out = (float*)d_out;

  float* msg = (float*)d_ws;  // (N,8) fp32, 256 KiB

  // ws is poisoned 0xAA before every call; atomics need zeros.
  hipMemsetAsync(msg, 0, (size_t)N * F * sizeof(float), stream);

  dim3 grid(N / RPB, JSPLIT);
  msg_pass_kernel<<<grid, dim3(256), 0, stream>>>(A, X, msg);

  mlp_kernel<<<dim3(N / 256), dim3(256), 0, stream>>>(
      msg, W_fm, b_fm, W_c1, b_c1, W_p1, b_p1, W_c2, b_c2, W_p2, b_p2, W_c3,
      b_c3, W_h, b_h, out);
}

// Round 2
// 427.711 us; speedup vs baseline: 1.1243x; 1.1243x over previous
//
#include <hip/hip_runtime.h>
#include <math.h>

#define N 8192
#define F 8
#define RPW 4                 // rows per wave
#define WPB 4                 // waves per block
#define RPB (RPW * WPB)       // 16 rows per block
#define JSPLIT 4
#define JCHUNK (N / JSPLIT)   // 2048 columns per block
#define TJ 256                // j-tile staged in LDS per iteration
#define NIT (JCHUNK / TJ)     // 8 iterations
#define THRF 0.9f

// msg[i][f] = sum_j max(A[i][j], fid_adj[i][j]) * X[j][f]
// fid_adj = 1 iff (xn_i . xn_j)^2 >= 0.9 and i != j, xn = X/(||X||+1e-12).
// A ~ U[0,1) so max(a,1)==1 exactly -> adj = sel ? 1.0f : a.
//
// v3:
//  - lane l owns tile-rows {k*64+l}; LDS tile stored f-major xT[f][256] so
//    inner reads are stride-1 dwords (bank-conflict-free); A-loads are 16
//    coalesced dword loads per tile.
//  - stage RAW X rows + t_j = 0.9*||X_j||^2; select test (xi.X_j)^2 >= t_j
//    (algebraically identical, kills per-j sqrt/rcp and per-pair *sj mul).
//  - j==i test hoisted out of the hot loop (diagonal always passes the
//    threshold); fixed post-reduction: v += (A[i][i]-1)*X[i][f].
//  - double-buffered LDS + one-tile-ahead A/X prefetch with two statically
//    named register sets (no conditional copies -> no scratch spills).
__global__ __launch_bounds__(256, 2) void msg_pass_kernel(
    const float* __restrict__ A, const float* __restrict__ X,
    float* __restrict__ msg) {
  __shared__ float xT[2][F][TJ];  // raw X tile, f-major
  __shared__ float tq[2][TJ];     // 0.9 * ||X_row||^2

  const int t = threadIdx.x;
  const int lane = t & 63;
  const int wave = t >> 6;
  const int i0 = blockIdx.x * RPB + wave * RPW;
  const int jbase = blockIdx.y * JCHUNK;

  // Normalized xi rows (wave-uniform) hoisted to SGPRs.
  float xi[RPW][F];
#pragma unroll
  for (int r = 0; r < RPW; ++r) {
    const float4* xp = (const float4*)(X + (size_t)(i0 + r) * F);
    const float4 lo = xp[0], hi = xp[1];
    const float ss = lo.x * lo.x + lo.y * lo.y + lo.z * lo.z + lo.w * lo.w +
                     hi.x * hi.x + hi.y * hi.y + hi.z * hi.z + hi.w * hi.w;
    const float inv = 1.0f / (sqrtf(ss) + 1e-12f);
    const float v[F] = {lo.x * inv, lo.y * inv, lo.z * inv, lo.w * inv,
                        hi.x * inv, hi.y * inv, hi.z * inv, hi.w * inv};
#pragma unroll
    for (int f = 0; f < F; ++f)
      xi[r][f] = __int_as_float(
          __builtin_amdgcn_readfirstlane(__float_as_int(v[f])));
  }

  float acc[RPW][F];
#pragma unroll
  for (int r = 0; r < RPW; ++r)
#pragma unroll
    for (int f = 0; f < F; ++f) acc[r][f] = 0.f;

  // Per-row A base pointers (already offset by this lane's column).
  const float* Ar[RPW];
#pragma unroll
  for (int r = 0; r < RPW; ++r)
    Ar[r] = A + (size_t)(i0 + r) * N + jbase + lane;

  auto loadA = [&](float av[RPW][4], int it) {
    const int o = it * TJ;
#pragma unroll
    for (int r = 0; r < RPW; ++r)
#pragma unroll
      for (int k = 0; k < 4; ++k) av[r][k] = Ar[r][o + k * 64];
  };
  auto loadX = [&](float4& lo, float4& hi, int it) {
    const float4* xp = (const float4*)(X + (size_t)(jbase + it * TJ + t) * F);
    lo = xp[0];
    hi = xp[1];
  };
  auto stage = [&](int b, const float4& lo, const float4& hi) {
    const float ss = lo.x * lo.x + lo.y * lo.y + lo.z * lo.z + lo.w * lo.w +
                     hi.x * hi.x + hi.y * hi.y + hi.z * hi.z + hi.w * hi.w;
    xT[b][0][t] = lo.x; xT[b][1][t] = lo.y;
    xT[b][2][t] = lo.z; xT[b][3][t] = lo.w;
    xT[b][4][t] = hi.x; xT[b][5][t] = hi.y;
    xT[b][6][t] = hi.z; xT[b][7][t] = hi.w;
    tq[b][t] = THRF * ss;
  };
  auto compute = [&](int b, const float av[RPW][4]) {
#pragma unroll
    for (int k = 0; k < 4; ++k) {
      const int row = k * 64 + lane;
      float xj[F];
#pragma unroll
      for (int f = 0; f < F; ++f) xj[f] = xT[b][f][row];
      const float tj = tq[b][row];
#pragma unroll
      for (int r = 0; r < RPW; ++r) {
        float dot = 0.f;
#pragma unroll
        for (int f = 0; f < F; ++f) dot = fmaf(xi[r][f], xj[f], dot);
        const float c = (dot * dot >= tj) ? 1.0f : av[r][k];
#pragma unroll
        for (int f = 0; f < F; ++f) acc[r][f] = fmaf(c, xj[f], acc[r][f]);
      }
    }
  };

  // Prologue: tile 0 resident in buf0 + av0.
  float av0[RPW][4], av1[RPW][4];
  float4 plo, phi;
  loadA(av0, 0);
  loadX(plo, phi, 0);
  stage(0, plo, phi);
  __syncthreads();

#pragma unroll 1
  for (int ith = 0; ith < NIT; ith += 2) {
    // even tile ith: compute buf0/av0, prefetch+stage tile ith+1 -> buf1/av1
    loadA(av1, ith + 1);
    loadX(plo, phi, ith + 1);
    compute(0, av0);
    stage(1, plo, phi);
    __syncthreads();
    // odd tile ith+1: compute buf1/av1, prefetch+stage ith+2 -> buf0/av0
    if (ith + 2 < NIT) {
      loadA(av0, ith + 2);
      loadX(plo, phi, ith + 2);
    }
    compute(1, av1);
    if (ith + 2 < NIT) stage(0, plo, phi);
    __syncthreads();
  }

  // Butterfly reduce; lane (r*8+f) owns the output atomic. Diagonal term
  // (added with coef 1.0 in-loop) repaired here: += (A[i][i]-1)*X[i][f].
  const bool diagblk = ((unsigned)(i0 - jbase) < (unsigned)JCHUNK);
#pragma unroll
  for (int r = 0; r < RPW; ++r) {
#pragma unroll
    for (int f = 0; f < F; ++f) {
      float v = acc[r][f];
#pragma unroll
      for (int off = 1; off < 64; off <<= 1) v += __shfl_xor(v, off, 64);
      if (lane == r * F + f) {
        if (diagblk) {
          const int i = i0 + r;
          const float aii = A[(size_t)i * N + i];
          const float xif = X[(size_t)i * F + f];
          v += (aii - 1.0f) * xif;
        }
        atomicAdd(msg + (size_t)(i0 + r) * F + f, v);
      }
    }
  }
}

__device__ __forceinline__ float sigmoidf_(float z) {
  return 1.0f / (1.0f + expf(-z));
}

// Per-node MLP chain. Weights are (fan_in, fan_out) row-major.
__global__ __launch_bounds__(256) void mlp_kernel(
    const float* __restrict__ msg,
    const float* __restrict__ W_fm, const float* __restrict__ b_fm,
    const float* __restrict__ W_c1, const float* __restrict__ b_c1,
    const float* __restrict__ W_p1, const float* __restrict__ b_p1,
    const float* __restrict__ W_c2, const float* __restrict__ b_c2,
    const float* __restrict__ W_p2, const float* __restrict__ b_p2,
    const float* __restrict__ W_c3, const float* __restrict__ b_c3,
    const float* __restrict__ W_h, const float* __restrict__ b_h,
    float* __restrict__ out) {
  const int i = blockIdx.x * blockDim.x + threadIdx.x;
  if (i >= N) return;

  float h0[8];
#pragma unroll
  for (int f = 0; f < 8; ++f) h0[f] = msg[(size_t)i * 8 + f];

  float h1[16];
#pragma unroll
  for (int o = 0; o < 16; ++o) {
    float z = b_fm[o];
#pragma unroll
    for (int k = 0; k < 8; ++k) z += h0[k] * W_fm[k * 16 + o];
    h1[o] = tanhf(z);
  }
  float h2[16];
#pragma unroll
  for (int o = 0; o < 16; ++o) {
    float z = b_c1[o];
#pragma unroll
    for (int k = 0; k < 16; ++k) z += h1[k] * W_c1[k * 16 + o];
    h2[o] = tanhf(z);
  }
  float h3[12];
#pragma unroll
  for (int o = 0; o < 12; ++o) {
    float z = b_p1[o];
#pragma unroll
    for (int k = 0; k < 16; ++k) z += h2[k] * W_p1[k * 12 + o];
    h3[o] = tanhf(z);
  }
  float h4[8];
#pragma unroll
  for (int o = 0; o < 8; ++o) {
    float z = b_c2[o];
#pragma unroll
    for (int k = 0; k < 12; ++k) z += h3[k] * W_c2[k * 8 + o];
    h4[o] = tanhf(z);
  }
  float h5[4];
#pragma unroll
  for (int o = 0; o < 4; ++o) {
    float z = b_p2[o];
#pragma unroll
    for (int k = 0; k < 8; ++k) z += h4[k] * W_p2[k * 4 + o];
    h5[o] = tanhf(z);
  }
  float h6[4];
#pragma unroll
  for (int o = 0; o < 4; ++o) {
    float z = b_c3[o];
#pragma unroll
    for (int k = 0; k < 4; ++k) z += h5[k] * W_c3[k * 4 + o];
    h6[o] = tanhf(z);
  }
  float z = b_h[0];
#pragma unroll
  for (int k = 0; k < 4; ++k) z += h6[k] * W_h[k];
  out[i] = sigmoidf_(z);
}

extern "C" void kernel_launch(void* const* d_in, const int* in_sizes, int n_in,
                              void* d_out, int out_size, void* d_ws,
                              size_t ws_size, hipStream_t stream) {
  const float* A = (const float*)d_in[0];
  const float* X = (const float*)d_in[1];
  const float* W_fm = (const float*)d_in[2];
  const float* b_fm = (const float*)d_in[3];
  const float* W_c1 = (const float*)d_in[4];
  const float* b_c1 = (const float*)d_in[5];
  const float* W_p1 = (const float*)d_in[6];
  const float* b_p1 = (const float*)d_in[7];
  const float* W_c2 = (const float*)d_in[8];
  const float* b_c2 = (const float*)d_in[9];
  const float* W_p2 = (const float*)d_in[10];
  const float* b_p2 = (const float*)d_in[11];
  const float* W_c3 = (const float*)d_in[12];
  const float* b_c3 = (const float*)d_in[13];
  const float* W_h = (const float*)d_in[14];
  const float* b_h = (const float*)d_in[15];
  float* out = (float*)d_out;

  float* msg = (float*)d_ws;  // (N,8) fp32, 256 KiB

  // ws is poisoned 0xAA before every call; atomics need zeros.
  hipMemsetAsync(msg, 0, (size_t)N * F * sizeof(float), stream);

  dim3 grid(N / RPB, JSPLIT);
  msg_pass_kernel<<<grid, dim3(256), 0, stream>>>(A, X, msg);

  mlp_kernel<<<dim3(N / 256), dim3(256), 0, stream>>>(
      msg, W_fm, b_fm, W_c1, b_c1, W_p1, b_p1, W_c2, b_c2, W_p2, b_p2, W_c3,
      b_c3, W_h, b_h, out);
}